// Round 4
// baseline (212.706 us; speedup 1.0000x reference)
//
#include <hip/hip_runtime.h>
#include <hip/hip_bf16.h>

// DenseContrastiveLossV2 on MI355X — round 5.
// Round-4 post-mortem: asm "+v" pin of 128-VGPR af => allocator SPILLED to
// scratch (VGPR_Count 120, k_pos 65.5us @ 1.7% MfmaUtil). Fixes:
//  (1) k_neg: 2x2 wave split -> af = 64 VGPR; af sourced from an LDS buffer
//      that is overwritten by B prefetches => remat impossible, pressure low
//      => af stays register-resident. Kills the 1.8 GB/launch L2 A-reload.
//  (2) k_pos: one 64x64 tile per block, grid (128,128); ~1350 active blocks
//      (~5/CU) instead of ~215 blocks x 4 serial tiles (1/CU, latency-bound).
//  (3) memsets folded into k_norm (6 -> 4 launches).

namespace {

constexpr int kC = 256;
constexpr int kHW = 96 * 96;   // 9216
constexpr int kT = 32;
constexpr int kV = 256;
constexpr int kM = kT * kV;    // 8192

typedef __attribute__((ext_vector_type(8))) short short8;  // 8 bf16
typedef __attribute__((ext_vector_type(4))) float f32x4;

__device__ inline unsigned short f2bf(float x) {
  __hip_bfloat16 h = __float2bfloat16(x);
  return __builtin_bit_cast(unsigned short, h);
}
__device__ inline float bf2f(unsigned short u) {
  unsigned int v = ((unsigned int)u) << 16;
  return __builtin_bit_cast(float, v);
}
__device__ inline void load_lds16(const unsigned short* g, unsigned short* l) {
  __builtin_amdgcn_global_load_lds(
      (const __attribute__((address_space(1))) void*)g,
      (__attribute__((address_space(3))) void*)l, 16, 0, 0);
}

// Stage one 64-row x 256-k bf16 tile (32 KB) of F into LDS, XOR-swizzled so
// ds_read_b128 consumers are conflict-free. LDS dst is wave-uniform base +
// lane*16 (global_load_lds requirement); the swizzle lives in the per-lane
// GLOBAL address (inverse-swizzle source + swizzled read = identity).
__device__ inline void stage_tile(const unsigned short* __restrict__ F,
                                  unsigned short* lds, int ct, int w,
                                  int lane) {
#pragma unroll
  for (int i = 0; i < 8; ++i) {
    const int n = w * 512 + i * 64 + lane;
    const int j = n >> 5;                      // row 0..63 of the tile
    const int m = (lane & 31) ^ (j & 31);      // swizzled 16B k-chunk
    load_lds16(F + ((size_t)(ct * 64 + j) << 8) + m * 8,
               lds + (size_t)(w * 512 + i * 64) * 8);
  }
}

}  // namespace

// ---------------- K0: gather (coalesced row staging) ----------------
__global__ __launch_bounds__(256) void k_gather(
    const float* __restrict__ feat, const int* __restrict__ binds,
    const int* __restrict__ sinds, unsigned short* __restrict__ FT) {
  const int b = (int)blockIdx.x;   // 0..7
  const int c = (int)blockIdx.y;   // 0..255
  __shared__ alignas(16) float row[kHW];
  __shared__ int s_match[kT + 1];
  if (threadIdx.x == 0) {
    int cnt = 0;
    for (int t = 0; t < kT; ++t)
      if (binds[t] == b) s_match[1 + cnt++] = t;
    s_match[0] = cnt;
  }
  __syncthreads();
  const int cnt = s_match[0];
  if (cnt == 0) return;
  const float4* src4 = (const float4*)(feat + ((size_t)b * kC + c) * kHW);
  for (int i = (int)threadIdx.x; i < kHW / 4; i += 256)
    ((float4*)row)[i] = src4[i];
  __syncthreads();
  unsigned short* dst = FT + (size_t)c * kM;
  for (int mi = 1; mi <= cnt; ++mi) {
    const int t = s_match[mi];
    const int p = sinds[t * kV + threadIdx.x];
    dst[t * kV + threadIdx.x] = f2bf(row[p]);
  }
}

// ---------------- K1: transpose + normalize (+ zero ns/out) ----------------
__global__ __launch_bounds__(256) void k_norm(
    const unsigned short* __restrict__ FT, unsigned short* __restrict__ F,
    float* __restrict__ ns, float* __restrict__ out, int out_size) {
  constexpr int PAD = 40;  // 32 vecs + 8 pad (80 B rows: breaks bank aliasing)
  const int v0 = (int)blockIdx.x * 32;
  __shared__ alignas(16) unsigned short tile[kC][PAD];
  __shared__ float part[8][32];
  __shared__ float s_inv[32];
  const int tid = (int)threadIdx.x;
  if (blockIdx.x == 0) {  // replaces the two hipMemsetAsync launches
    for (int i = tid; i < kM; i += 256) ns[i] = 0.f;
    for (int i = tid; i < out_size; i += 256) out[i] = 0.f;
  }
  {
    const int p4 = tid & 3, cb = tid >> 2;  // 4x16B per 64B c-row
    for (int c = cb; c < kC; c += 64) {
      int4 d = *(const int4*)(FT + (size_t)c * kM + v0 + p4 * 8);
      *(int4*)&tile[c][p4 * 8] = d;
    }
  }
  __syncthreads();
  {
    const int v = tid & 31, oct = tid >> 5;
    float ss = 0.f;
    for (int c = oct * 32; c < oct * 32 + 32; ++c) {
      float x = bf2f(tile[c][v]);
      ss += x * x;
    }
    part[oct][v] = ss;
  }
  __syncthreads();
  if (tid < 32) {
    float ss = 0.f;
#pragma unroll
    for (int o = 0; o < 8; ++o) ss += part[o][tid];
    s_inv[tid] = 1.0f / fmaxf(sqrtf(ss), 1e-12f);
  }
  __syncthreads();
#pragma unroll
  for (int p = 0; p < 4; ++p) {
    const int chunk = p * 256 + tid;
    const int v = chunk >> 5, c0 = (chunk & 31) << 3;
    const float inv = s_inv[v];
    alignas(16) unsigned short o[8];
#pragma unroll
    for (int k = 0; k < 8; ++k) o[k] = f2bf(bf2f(tile[c0 + k][v]) * inv);
    *(int4*)(F + (size_t)(v0 + v) * kC + c0) = *(const int4*)o;
  }
}

// ---------------- K2: negative sweep -> ns[row] ----------------
// grid: 512 1-D blocks; XCD decode: 2 XCDs own each 2048-col panel cx so the
// 1 MB B-panel stays L2-resident per XCD. Wave layout: 2x2 (wr,wc), each wave
// computes 32 rows x 32 cols; af[2][8] = 64 VGPR, read from LDS Bt[0] (the
// staged A tile) which is then OVERWRITTEN by B prefetches -> compiler cannot
// rematerialize the af loads, and at ~130 VGPR pressure it has no reason to
// spill -> af is register-resident across the tile loop.
__global__ __launch_bounds__(256, 2) void k_neg(
    const unsigned short* __restrict__ F, const int* __restrict__ labels,
    float* __restrict__ ns) {
  const int tid = (int)threadIdx.x;
  const int w = tid >> 6, lane = tid & 63, q = lane >> 4, l16 = lane & 15;
  const int wr = w >> 1, wc = w & 1;
  const int bid = (int)blockIdx.x;          // 0..511
  const int xcd = bid & 7, slot = bid >> 3; // slot 0..63
  const int cx = xcd >> 1;                  // 0..3 (2 XCDs per panel)
  const int row0 = (((slot << 1) | (xcd & 1))) * 64;  // rowblock 0..127
  __shared__ alignas(16) unsigned short Bt[2][64 * kC];  // 2 x 32 KB, swizzled
  __shared__ int s_lab[kT];
  __shared__ int s_tiles[32];
  __shared__ int s_nt;
  __shared__ float s_red[4][32];
  if (tid < kT) s_lab[tid] = labels[tid];
  __syncthreads();
  const int labr = s_lab[row0 >> 8];
  if (tid == 0) {  // compacted negative-tile list (block-uniform skip)
    int n = 0;
    for (int ct = cx * 32; ct < cx * 32 + 32; ++ct)
      if (s_lab[ct >> 2] != labr) s_tiles[n++] = ct;
    s_nt = n;
  }
  __syncthreads();
  const int nt = s_nt;
  if (nt == 0) return;

  // Prologue: stage A tile (this block's 64 rows) into Bt[0] and B tile 0
  // into Bt[1]; one barrier drains both.
  stage_tile(F, Bt[0], row0 >> 6, w, lane);
  stage_tile(F, Bt[1], s_tiles[0], w, lane);
  __syncthreads();

  // Read af from LDS: wave (wr,wc) needs rows row0 + wr*32 + rg*16 + l16.
  short8 af[2][8];
#pragma unroll
  for (int rg = 0; rg < 2; ++rg) {
    const int ja = wr * 32 + rg * 16 + l16;
    const unsigned short* arow = Bt[0] + ja * kC;
#pragma unroll
    for (int ks = 0; ks < 8; ++ks)
      af[rg][ks] = *(const short8*)(arow + (((ks * 4 + q) ^ (ja & 31)) << 3));
  }
  __syncthreads();  // all waves' af reads complete before Bt[0] is overwritten

  // B columns for this wave: jb = wc*32 + cg*16 + l16.
  const int jb0 = wc * 32 + l16, jb1 = wc * 32 + 16 + l16;
  const unsigned short* bc0base = (const unsigned short*)Bt + jb0 * kC;
  const unsigned short* bc1base = (const unsigned short*)Bt + jb1 * kC;
  int bofs0[8], bofs1[8];
#pragma unroll
  for (int ks = 0; ks < 8; ++ks) {
    bofs0[ks] = (((ks * 4 + q) ^ (jb0 & 31)) << 3);
    bofs1[ks] = (((ks * 4 + q) ^ (jb1 & 31)) << 3);
  }

  float sacc[2][4] = {};
  for (int it = 0; it < nt; ++it) {
    // it=0 overwrites Bt[0] (A tile) -- af already in registers.
    if (it + 1 < nt) stage_tile(F, Bt[it & 1], s_tiles[it + 1], w, lane);
    const size_t boff = (size_t)(1 ^ (it & 1)) * (64 * kC);
    const unsigned short* bc0 = bc0base + boff;
    const unsigned short* bc1 = bc1base + boff;
    f32x4 a00 = {0.f, 0.f, 0.f, 0.f}, a01 = a00, a10 = a00, a11 = a00;
#pragma unroll
    for (int ks = 0; ks < 8; ++ks) {
      short8 b0 = *(const short8*)(bc0 + bofs0[ks]);
      short8 b1 = *(const short8*)(bc1 + bofs1[ks]);
      a00 = __builtin_amdgcn_mfma_f32_16x16x32_bf16(af[0][ks], b0, a00, 0, 0, 0);
      a01 = __builtin_amdgcn_mfma_f32_16x16x32_bf16(af[0][ks], b1, a01, 0, 0, 0);
      a10 = __builtin_amdgcn_mfma_f32_16x16x32_bf16(af[1][ks], b0, a10, 0, 0, 0);
      a11 = __builtin_amdgcn_mfma_f32_16x16x32_bf16(af[1][ks], b1, a11, 0, 0, 0);
    }
#pragma unroll
    for (int r = 0; r < 4; ++r) {
      sacc[0][r] += __expf(fmaf(a00[r], 2.f, -2.f)) +
                    __expf(fmaf(a01[r], 2.f, -2.f));
      sacc[1][r] += __expf(fmaf(a10[r], 2.f, -2.f)) +
                    __expf(fmaf(a11[r], 2.f, -2.f));
    }
    __syncthreads();  // drains this iter's prefetch (hidden under compute)
  }

  // Row-sum: lanes sharing q (same output row) reduce over l16 (16 columns);
  // each lane's sacc already sums its two cg columns.
#pragma unroll
  for (int rg = 0; rg < 2; ++rg)
#pragma unroll
    for (int r = 0; r < 4; ++r) {
      float v = sacc[rg][r];
      v += __shfl_xor(v, 1, 64);
      v += __shfl_xor(v, 2, 64);
      v += __shfl_xor(v, 4, 64);
      v += __shfl_xor(v, 8, 64);
      if (l16 == 0) s_red[w][rg * 16 + q * 4 + r] = v;
    }
  __syncthreads();
  if (tid < 64) {
    const int rr = tid >> 5, e = tid & 31;  // row = row0 + rr*32 + e
    float v = s_red[rr * 2][e] + s_red[rr * 2 + 1][e];
    atomicAdd(&ns[row0 + tid], v);
  }
}

// ---------------- K3: positive sweep -> loss ----------------
// grid (128,128): block (bj,bi) computes ONE 64x64 tile iff the row/col
// labels match (~1350 active blocks, ~5/CU -> TLP hides staging latency).
__global__ __launch_bounds__(256, 2) void k_pos(
    const unsigned short* __restrict__ F, const int* __restrict__ labels,
    const float* __restrict__ ns, float* __restrict__ out) {
  const int tid = (int)threadIdx.x;
  const int w = tid >> 6, lane = tid & 63, q = lane >> 4, l16 = lane & 15;
  const int bi = (int)blockIdx.y;  // row block 0..127
  const int bj = (int)blockIdx.x;  // col block 0..127
  __shared__ alignas(16) unsigned short Bt[64 * kC];  // 32 KB, swizzled
  __shared__ int s_lab[kT];
  __shared__ float s_pos[4];
  if (tid < kT) s_lab[tid] = labels[tid];
  __syncthreads();
  const int labr = s_lab[bi >> 2];
  if (s_lab[bj >> 2] != labr) return;  // block-uniform
  const int row0 = bi * 64;

  stage_tile(F, Bt, bj, w, lane);  // async; drained by the barrier below

  short8 af[4][8];
#pragma unroll
  for (int rg = 0; rg < 4; ++rg)
#pragma unroll
    for (int ks = 0; ks < 8; ++ks)
      af[rg][ks] = *(const short8*)((const short*)F +
                                    (size_t)(row0 + rg * 16 + l16) * kC +
                                    ks * 32 + q * 8);
  const int j2 = w * 16 + l16;
  const unsigned short* bcol = Bt + j2 * kC;
  int bofs[8];
#pragma unroll
  for (int ks = 0; ks < 8; ++ks)
    bofs[ks] = ((ks * 4 + q) ^ (j2 & 31)) << 3;

  float nsv[4][4];
#pragma unroll
  for (int rg = 0; rg < 4; ++rg)
#pragma unroll
    for (int r = 0; r < 4; ++r)
      nsv[rg][r] = ns[row0 + rg * 16 + q * 4 + r];

  __syncthreads();  // B tile staged

  f32x4 acc[4];
#pragma unroll
  for (int rg = 0; rg < 4; ++rg) acc[rg] = (f32x4){0.f, 0.f, 0.f, 0.f};
#pragma unroll
  for (int ks = 0; ks < 8; ++ks) {
    short8 bf = *(const short8*)(bcol + bofs[ks]);
#pragma unroll
    for (int rg = 0; rg < 4; ++rg)
      acc[rg] = __builtin_amdgcn_mfma_f32_16x16x32_bf16(af[rg][ks], bf,
                                                        acc[rg], 0, 0, 0);
  }
  const int jcol = bj * 64 + j2;
  float pos = 0.f;
#pragma unroll
  for (int rg = 0; rg < 4; ++rg)
#pragma unroll
    for (int r = 0; r < 4; ++r) {
      const int i = row0 + rg * 16 + q * 4 + r;
      if (i != jcol) {
        float d = fmaf(acc[rg][r], 2.f, -2.f);
        pos += d - __logf(__expf(d) + nsv[rg][r]);
      }
    }
#pragma unroll
  for (int m = 1; m < 64; m <<= 1) pos += __shfl_xor(pos, m, 64);
  if (lane == 0) s_pos[w] = pos;
  __syncthreads();
  if (tid == 0) {
    float tot = s_pos[0] + s_pos[1] + s_pos[2] + s_pos[3];
    int matches = 0;
    for (int t = 0; t < kT; ++t) matches += (s_lab[t] == labr) ? 1 : 0;
    const float cnt = (float)(matches * kV - 1);
    atomicAdd(out, -tot / (cnt * (float)kM));
  }
}

extern "C" void kernel_launch(void* const* d_in, const int* in_sizes, int n_in,
                              void* d_out, int out_size, void* d_ws,
                              size_t ws_size, hipStream_t stream) {
  const float* feat = (const float*)d_in[0];
  const int* binds = (const int*)d_in[1];
  const int* sinds = (const int*)d_in[2];
  const int* labels = (const int*)d_in[3];
  float* out = (float*)d_out;
  unsigned short* FT = (unsigned short*)d_ws;            // 4 MB  [256][8192]
  unsigned short* F = FT + (size_t)kC * kM;              // 4 MB  [8192][256]
  float* ns = (float*)(F + (size_t)kM * kC);             // 32 KB [8192]

  k_gather<<<dim3(8, kC), 256, 0, stream>>>(feat, binds, sinds, FT);
  k_norm<<<kM / 32, 256, 0, stream>>>(FT, F, ns, out, out_size);
  k_neg<<<dim3(512), 256, 0, stream>>>(F, labels, ns);
  k_pos<<<dim3(128, 128), 256, 0, stream>>>(F, labels, ns, out);
}

// Round 5
// 183.569 us; speedup vs baseline: 1.1587x; 1.1587x over previous
//
#include <hip/hip_runtime.h>
#include <hip/hip_bf16.h>

// DenseContrastiveLossV2 on MI355X — round 6.
// Round-5 post-mortem: k_pos (grid 128x128, 92% dead blocks) cost ~56us with
// MfmaUtil 1.9% — dead-block churn (LDS alloc + label load + retire for 15k
// blocks through ~512 resident slots) dominated, scaling with TOTAL blocks
// across rounds 4/5, not active ones. Fix: k_prep builds a compacted
// active-tile list; k_pos grid-strides over it (768 blocks, all active,
// 2x2 wave split => af[2][8]=64 VGPR, no remat pressure).
// K0 k_prep   : zero ns/out, per-t loss scales, active (bi,bj) list.
// K1 k_gather : unchanged.
// K2 k_norm   : unchanged (zeroing moved to k_prep).
// K3 k_neg    : unchanged from round 5 (passed; perf TBD in top-5).
// K4 k_pos    : list-driven, one 64x64 tile per list entry.

namespace {

constexpr int kC = 256;
constexpr int kHW = 96 * 96;   // 9216
constexpr int kT = 32;
constexpr int kV = 256;
constexpr int kM = kT * kV;    // 8192

typedef __attribute__((ext_vector_type(8))) short short8;  // 8 bf16
typedef __attribute__((ext_vector_type(4))) float f32x4;

__device__ inline unsigned short f2bf(float x) {
  __hip_bfloat16 h = __float2bfloat16(x);
  return __builtin_bit_cast(unsigned short, h);
}
__device__ inline float bf2f(unsigned short u) {
  unsigned int v = ((unsigned int)u) << 16;
  return __builtin_bit_cast(float, v);
}
__device__ inline void load_lds16(const unsigned short* g, unsigned short* l) {
  __builtin_amdgcn_global_load_lds(
      (const __attribute__((address_space(1))) void*)g,
      (__attribute__((address_space(3))) void*)l, 16, 0, 0);
}

// Stage one 64-row x 256-k bf16 tile (32 KB) of F into LDS, XOR-swizzled so
// ds_read_b128 consumers are conflict-free. LDS dst is wave-uniform base +
// lane*16 (global_load_lds requirement); the swizzle lives in the per-lane
// GLOBAL address (inverse-swizzle source + swizzled read = identity).
__device__ inline void stage_tile(const unsigned short* __restrict__ F,
                                  unsigned short* lds, int ct, int w,
                                  int lane) {
#pragma unroll
  for (int i = 0; i < 8; ++i) {
    const int n = w * 512 + i * 64 + lane;
    const int j = n >> 5;                      // row 0..63 of the tile
    const int m = (lane & 31) ^ (j & 31);      // swizzled 16B k-chunk
    load_lds16(F + ((size_t)(ct * 64 + j) << 8) + m * 8,
               lds + (size_t)(w * 512 + i * 64) * 8);
  }
}

}  // namespace

// ---------------- K0: prep (zero ns/out, scales, active-tile list) --------
__global__ __launch_bounds__(256) void k_prep(
    const int* __restrict__ labels, float* __restrict__ ns,
    float* __restrict__ out, int out_size, int* __restrict__ nact,
    ushort2* __restrict__ list, float* __restrict__ cscale) {
  const int tid = (int)threadIdx.x;
  __shared__ int s_lab[kT];
  if (tid < kT) s_lab[tid] = labels[tid];
  if (tid == 0) *nact = 0;
  for (int i = tid; i < kM; i += 256) ns[i] = 0.f;
  for (int i = tid; i < out_size; i += 256) out[i] = 0.f;
  __syncthreads();
  if (tid < kT) {
    int m = 0;
    for (int u = 0; u < kT; ++u) m += (s_lab[u] == s_lab[tid]) ? 1 : 0;
    cscale[tid] = 1.f / ((float)(m * kV - 1) * (float)kM);
  }
  for (int p = tid; p < kT * kT; p += 256) {
    const int ti = p >> 5, tj = p & 31;
    if (s_lab[ti] == s_lab[tj]) {
      int base = atomicAdd(nact, 16);
#pragma unroll
      for (int a = 0; a < 4; ++a)
#pragma unroll
        for (int b = 0; b < 4; ++b) {
          ushort2 e;
          e.x = (unsigned short)(ti * 4 + a);  // bi 0..127
          e.y = (unsigned short)(tj * 4 + b);  // bj 0..127
          list[base + a * 4 + b] = e;
        }
    }
  }
}

// ---------------- K1: gather (coalesced row staging) ----------------
__global__ __launch_bounds__(256) void k_gather(
    const float* __restrict__ feat, const int* __restrict__ binds,
    const int* __restrict__ sinds, unsigned short* __restrict__ FT) {
  const int b = (int)blockIdx.x;   // 0..7
  const int c = (int)blockIdx.y;   // 0..255
  __shared__ alignas(16) float row[kHW];
  __shared__ int s_match[kT + 1];
  if (threadIdx.x == 0) {
    int cnt = 0;
    for (int t = 0; t < kT; ++t)
      if (binds[t] == b) s_match[1 + cnt++] = t;
    s_match[0] = cnt;
  }
  __syncthreads();
  const int cnt = s_match[0];
  if (cnt == 0) return;
  const float4* src4 = (const float4*)(feat + ((size_t)b * kC + c) * kHW);
  for (int i = (int)threadIdx.x; i < kHW / 4; i += 256)
    ((float4*)row)[i] = src4[i];
  __syncthreads();
  unsigned short* dst = FT + (size_t)c * kM;
  for (int mi = 1; mi <= cnt; ++mi) {
    const int t = s_match[mi];
    const int p = sinds[t * kV + threadIdx.x];
    dst[t * kV + threadIdx.x] = f2bf(row[p]);
  }
}

// ---------------- K2: transpose + normalize ----------------
__global__ __launch_bounds__(256) void k_norm(
    const unsigned short* __restrict__ FT, unsigned short* __restrict__ F) {
  constexpr int PAD = 40;  // 32 vecs + 8 pad (80 B rows: breaks bank aliasing)
  const int v0 = (int)blockIdx.x * 32;
  __shared__ alignas(16) unsigned short tile[kC][PAD];
  __shared__ float part[8][32];
  __shared__ float s_inv[32];
  const int tid = (int)threadIdx.x;
  {
    const int p4 = tid & 3, cb = tid >> 2;  // 4x16B per 64B c-row
    for (int c = cb; c < kC; c += 64) {
      int4 d = *(const int4*)(FT + (size_t)c * kM + v0 + p4 * 8);
      *(int4*)&tile[c][p4 * 8] = d;
    }
  }
  __syncthreads();
  {
    const int v = tid & 31, oct = tid >> 5;
    float ss = 0.f;
    for (int c = oct * 32; c < oct * 32 + 32; ++c) {
      float x = bf2f(tile[c][v]);
      ss += x * x;
    }
    part[oct][v] = ss;
  }
  __syncthreads();
  if (tid < 32) {
    float ss = 0.f;
#pragma unroll
    for (int o = 0; o < 8; ++o) ss += part[o][tid];
    s_inv[tid] = 1.0f / fmaxf(sqrtf(ss), 1e-12f);
  }
  __syncthreads();
#pragma unroll
  for (int p = 0; p < 4; ++p) {
    const int chunk = p * 256 + tid;
    const int v = chunk >> 5, c0 = (chunk & 31) << 3;
    const float inv = s_inv[v];
    alignas(16) unsigned short o[8];
#pragma unroll
    for (int k = 0; k < 8; ++k) o[k] = f2bf(bf2f(tile[c0 + k][v]) * inv);
    *(int4*)(F + (size_t)(v0 + v) * kC + c0) = *(const int4*)o;
  }
}

// ---------------- K3: negative sweep -> ns[row] (unchanged, round 5) ------
__global__ __launch_bounds__(256, 2) void k_neg(
    const unsigned short* __restrict__ F, const int* __restrict__ labels,
    float* __restrict__ ns) {
  const int tid = (int)threadIdx.x;
  const int w = tid >> 6, lane = tid & 63, q = lane >> 4, l16 = lane & 15;
  const int wr = w >> 1, wc = w & 1;
  const int bid = (int)blockIdx.x;          // 0..511
  const int xcd = bid & 7, slot = bid >> 3; // slot 0..63
  const int cx = xcd >> 1;                  // 0..3 (2 XCDs per panel)
  const int row0 = (((slot << 1) | (xcd & 1))) * 64;  // rowblock 0..127
  __shared__ alignas(16) unsigned short Bt[2][64 * kC];  // 2 x 32 KB, swizzled
  __shared__ int s_lab[kT];
  __shared__ int s_tiles[32];
  __shared__ int s_nt;
  __shared__ float s_red[4][32];
  if (tid < kT) s_lab[tid] = labels[tid];
  __syncthreads();
  const int labr = s_lab[row0 >> 8];
  if (tid == 0) {  // compacted negative-tile list (block-uniform skip)
    int n = 0;
    for (int ct = cx * 32; ct < cx * 32 + 32; ++ct)
      if (s_lab[ct >> 2] != labr) s_tiles[n++] = ct;
    s_nt = n;
  }
  __syncthreads();
  const int nt = s_nt;
  if (nt == 0) return;

  // Prologue: stage A tile (this block's 64 rows) into Bt[0] and B tile 0
  // into Bt[1]; one barrier drains both.
  stage_tile(F, Bt[0], row0 >> 6, w, lane);
  stage_tile(F, Bt[1], s_tiles[0], w, lane);
  __syncthreads();

  // Read af from LDS: wave (wr,wc) needs rows row0 + wr*32 + rg*16 + l16.
  short8 af[2][8];
#pragma unroll
  for (int rg = 0; rg < 2; ++rg) {
    const int ja = wr * 32 + rg * 16 + l16;
    const unsigned short* arow = Bt[0] + ja * kC;
#pragma unroll
    for (int ks = 0; ks < 8; ++ks)
      af[rg][ks] = *(const short8*)(arow + (((ks * 4 + q) ^ (ja & 31)) << 3));
  }
  __syncthreads();  // all waves' af reads complete before Bt[0] is overwritten

  const int jb0 = wc * 32 + l16, jb1 = wc * 32 + 16 + l16;
  const unsigned short* bc0base = (const unsigned short*)Bt + jb0 * kC;
  const unsigned short* bc1base = (const unsigned short*)Bt + jb1 * kC;
  int bofs0[8], bofs1[8];
#pragma unroll
  for (int ks = 0; ks < 8; ++ks) {
    bofs0[ks] = (((ks * 4 + q) ^ (jb0 & 31)) << 3);
    bofs1[ks] = (((ks * 4 + q) ^ (jb1 & 31)) << 3);
  }

  float sacc[2][4] = {};
  for (int it = 0; it < nt; ++it) {
    // it=0 overwrites Bt[0] (A tile) -- af already in registers.
    if (it + 1 < nt) stage_tile(F, Bt[it & 1], s_tiles[it + 1], w, lane);
    const size_t boff = (size_t)(1 ^ (it & 1)) * (64 * kC);
    const unsigned short* bc0 = bc0base + boff;
    const unsigned short* bc1 = bc1base + boff;
    f32x4 a00 = {0.f, 0.f, 0.f, 0.f}, a01 = a00, a10 = a00, a11 = a00;
#pragma unroll
    for (int ks = 0; ks < 8; ++ks) {
      short8 b0 = *(const short8*)(bc0 + bofs0[ks]);
      short8 b1 = *(const short8*)(bc1 + bofs1[ks]);
      a00 = __builtin_amdgcn_mfma_f32_16x16x32_bf16(af[0][ks], b0, a00, 0, 0, 0);
      a01 = __builtin_amdgcn_mfma_f32_16x16x32_bf16(af[0][ks], b1, a01, 0, 0, 0);
      a10 = __builtin_amdgcn_mfma_f32_16x16x32_bf16(af[1][ks], b0, a10, 0, 0, 0);
      a11 = __builtin_amdgcn_mfma_f32_16x16x32_bf16(af[1][ks], b1, a11, 0, 0, 0);
    }
#pragma unroll
    for (int r = 0; r < 4; ++r) {
      sacc[0][r] += __expf(fmaf(a00[r], 2.f, -2.f)) +
                    __expf(fmaf(a01[r], 2.f, -2.f));
      sacc[1][r] += __expf(fmaf(a10[r], 2.f, -2.f)) +
                    __expf(fmaf(a11[r], 2.f, -2.f));
    }
    __syncthreads();  // drains this iter's prefetch (hidden under compute)
  }

#pragma unroll
  for (int rg = 0; rg < 2; ++rg)
#pragma unroll
    for (int r = 0; r < 4; ++r) {
      float v = sacc[rg][r];
      v += __shfl_xor(v, 1, 64);
      v += __shfl_xor(v, 2, 64);
      v += __shfl_xor(v, 4, 64);
      v += __shfl_xor(v, 8, 64);
      if (l16 == 0) s_red[w][rg * 16 + q * 4 + r] = v;
    }
  __syncthreads();
  if (tid < 64) {
    const int rr = tid >> 5, e = tid & 31;  // row = row0 + rr*32 + e
    float v = s_red[rr * 2][e] + s_red[rr * 2 + 1][e];
    atomicAdd(&ns[row0 + tid], v);
  }
}

// ---------------- K4: positive sweep -> loss (list-driven) ----------------
// 768 blocks grid-stride the compacted active-tile list; every block does
// real work. 2x2 wave split: af[2][8] = 64 VGPR (no remat pressure).
__global__ __launch_bounds__(256, 3) void k_pos(
    const unsigned short* __restrict__ F, const float* __restrict__ ns,
    const int* __restrict__ nact, const ushort2* __restrict__ list,
    const float* __restrict__ cscale, float* __restrict__ out) {
  const int tid = (int)threadIdx.x;
  const int w = tid >> 6, lane = tid & 63, q = lane >> 4, l16 = lane & 15;
  const int wr = w >> 1, wc = w & 1;
  __shared__ alignas(16) unsigned short Bt[64 * kC];  // 32 KB, swizzled
  __shared__ float s_pos[4];
  const int n = *nact;

  const int jb0 = wc * 32 + l16, jb1 = wc * 32 + 16 + l16;
  int bofs0[8], bofs1[8];
#pragma unroll
  for (int ks = 0; ks < 8; ++ks) {
    bofs0[ks] = (((ks * 4 + q) ^ (jb0 & 31)) << 3);
    bofs1[ks] = (((ks * 4 + q) ^ (jb1 & 31)) << 3);
  }
  const unsigned short* bc0 = (const unsigned short*)Bt + jb0 * kC;
  const unsigned short* bc1 = (const unsigned short*)Bt + jb1 * kC;

  float pos = 0.f;
  for (int idx = (int)blockIdx.x; idx < n; idx += (int)gridDim.x) {
    const ushort2 e = list[idx];
    const int bi = e.x, bj = e.y;
    stage_tile(F, Bt, bj, w, lane);  // async; drained at the barrier below

    short8 af[2][8];
#pragma unroll
    for (int rg = 0; rg < 2; ++rg) {
      const int row = bi * 64 + wr * 32 + rg * 16 + l16;
#pragma unroll
      for (int ks = 0; ks < 8; ++ks)
        af[rg][ks] = *(const short8*)((const short*)F + (size_t)row * kC +
                                      ks * 32 + q * 8);
    }
    float nsv[2][4];
#pragma unroll
    for (int rg = 0; rg < 2; ++rg)
#pragma unroll
      for (int r = 0; r < 4; ++r)
        nsv[rg][r] = ns[bi * 64 + wr * 32 + rg * 16 + q * 4 + r];
    const float scale = cscale[bi >> 2];

    __syncthreads();  // B tile staged (+ af/nsv drained by vmcnt)

    f32x4 a00 = {0.f, 0.f, 0.f, 0.f}, a01 = a00, a10 = a00, a11 = a00;
#pragma unroll
    for (int ks = 0; ks < 8; ++ks) {
      short8 b0 = *(const short8*)(bc0 + bofs0[ks]);
      short8 b1 = *(const short8*)(bc1 + bofs1[ks]);
      a00 = __builtin_amdgcn_mfma_f32_16x16x32_bf16(af[0][ks], b0, a00, 0, 0, 0);
      a01 = __builtin_amdgcn_mfma_f32_16x16x32_bf16(af[0][ks], b1, a01, 0, 0, 0);
      a10 = __builtin_amdgcn_mfma_f32_16x16x32_bf16(af[1][ks], b0, a10, 0, 0, 0);
      a11 = __builtin_amdgcn_mfma_f32_16x16x32_bf16(af[1][ks], b1, a11, 0, 0, 0);
    }

    float tpos = 0.f;
#pragma unroll
    for (int rg = 0; rg < 2; ++rg)
#pragma unroll
      for (int cg = 0; cg < 2; ++cg) {
        const f32x4 acc = (rg == 0) ? (cg == 0 ? a00 : a01)
                                    : (cg == 0 ? a10 : a11);
        const int jc = bj * 64 + wc * 32 + cg * 16 + l16;
#pragma unroll
        for (int r = 0; r < 4; ++r) {
          const int i = bi * 64 + wr * 32 + rg * 16 + q * 4 + r;
          if (i != jc) {
            float d = fmaf(acc[r], 2.f, -2.f);
            tpos += d - __logf(__expf(d) + nsv[rg][r]);
          }
        }
      }
    pos += scale * tpos;
    __syncthreads();  // all waves done reading Bt before next stage
  }

#pragma unroll
  for (int m = 1; m < 64; m <<= 1) pos += __shfl_xor(pos, m, 64);
  if (lane == 0) s_pos[w] = pos;
  __syncthreads();
  if (tid == 0)
    atomicAdd(out, -(s_pos[0] + s_pos[1] + s_pos[2] + s_pos[3]));
}

extern "C" void kernel_launch(void* const* d_in, const int* in_sizes, int n_in,
                              void* d_out, int out_size, void* d_ws,
                              size_t ws_size, hipStream_t stream) {
  const float* feat = (const float*)d_in[0];
  const int* binds = (const int*)d_in[1];
  const int* sinds = (const int*)d_in[2];
  const int* labels = (const int*)d_in[3];
  float* out = (float*)d_out;
  unsigned short* FT = (unsigned short*)d_ws;            // 4 MB  [256][8192]
  unsigned short* F = FT + (size_t)kC * kM;              // 4 MB  [8192][256]
  float* ns = (float*)(F + (size_t)kM * kC);             // 32 KB [8192]
  int* nact = (int*)(ns + kM);                           // 4 B (+pad)
  float* cscale = (float*)(nact + 8);                    // 128 B [32]
  ushort2* list = (ushort2*)(cscale + 32);               // 64 KB [16384]

  k_prep<<<1, 256, 0, stream>>>(labels, ns, out, out_size, nact, list, cscale);
  k_gather<<<dim3(8, kC), 256, 0, stream>>>(feat, binds, sinds, FT);
  k_norm<<<kM / 32, 256, 0, stream>>>(FT, F);
  k_neg<<<dim3(512), 256, 0, stream>>>(F, labels, ns);
  k_pos<<<768, 256, 0, stream>>>(F, ns, nact, list, cscale, out);
}

// Round 6
// 178.508 us; speedup vs baseline: 1.1916x; 1.0284x over previous
//
#include <hip/hip_runtime.h>
#include <hip/hip_bf16.h>

// DenseContrastiveLossV2 on MI355X — round 7.
// Round-6 post-mortem: af IS resident (VGPR=88) yet k_neg stuck at 58us /
// MfmaUtil 21%. Invariant across 3 schedules: occupancy 18.7% (LDS-capped
// 2 blocks/CU, grid exactly 2/CU) => staging(1100cyc) + MFMA(1240cyc) + ds
// serialize per tile-pair (2490cyc measured). Fix: BM=128 8-wave blocks
// (2x compute per staged tile, half the B L2-traffic), SINGLE 32KB buffer
// (LDS 33.3KB) + VGPR<=128 via __launch_bounds__(512,4) => 2 blocks x 8
// waves = 16 waves/CU; TLP hides the stage/barrier (m114) instead of dbuf.
// K0 k_prep   : 64 blocks zero ns; block 0 builds scales + active-tile list.
// K1 k_gather : unchanged.
// K2 k_norm   : unchanged.
// K3 k_neg    : BM=128 x BN=64 tiles, panel=1024 cols XCD-pinned, A via
//               two-pass LDS-prologue into af[2][8] regs (residency proven).
// K4 k_pos    : unchanged (list-driven, passed, out of top-5).

namespace {

constexpr int kC = 256;
constexpr int kHW = 96 * 96;   // 9216
constexpr int kT = 32;
constexpr int kV = 256;
constexpr int kM = kT * kV;    // 8192

typedef __attribute__((ext_vector_type(8))) short short8;  // 8 bf16
typedef __attribute__((ext_vector_type(4))) float f32x4;

__device__ inline unsigned short f2bf(float x) {
  __hip_bfloat16 h = __float2bfloat16(x);
  return __builtin_bit_cast(unsigned short, h);
}
__device__ inline float bf2f(unsigned short u) {
  unsigned int v = ((unsigned int)u) << 16;
  return __builtin_bit_cast(float, v);
}
__device__ inline void load_lds16(const unsigned short* g, unsigned short* l) {
  __builtin_amdgcn_global_load_lds(
      (const __attribute__((address_space(1))) void*)g,
      (__attribute__((address_space(3))) void*)l, 16, 0, 0);
}

// Stage one 64-row x 256-k bf16 tile (32 KB) of F into LDS with 256 threads,
// XOR-swizzled (inverse-swizzled global source + linear LDS dst, so the
// swizzled ds_read is conflict-free). Rows here are F rows = B cols.
__device__ inline void stage_tile4(const unsigned short* __restrict__ F,
                                   unsigned short* lds, int ct, int tid) {
#pragma unroll
  for (int i = 0; i < 8; ++i) {
    const int n = i * 256 + tid;               // 16B-slot 0..2047
    const int j = n >> 5;                      // row 0..63
    const int m = (n & 31) ^ (j & 31);         // swizzled 16B k-chunk
    load_lds16(F + ((size_t)(ct * 64 + j) << 8) + m * 8,
               lds + (size_t)n * 8);
  }
}

// Same, with 512 threads (8-wave blocks).
__device__ inline void stage_tile8(const unsigned short* __restrict__ F,
                                   unsigned short* lds, int ct, int tid) {
#pragma unroll
  for (int i = 0; i < 4; ++i) {
    const int n = i * 512 + tid;               // 16B-slot 0..2047
    const int j = n >> 5;                      // row 0..63
    const int m = (n & 31) ^ (j & 31);         // swizzled 16B k-chunk
    load_lds16(F + ((size_t)(ct * 64 + j) << 8) + m * 8,
               lds + (size_t)n * 8);
  }
}

}  // namespace

// ---------------- K0: prep (zero ns/out, scales, active-tile list) --------
__global__ __launch_bounds__(256) void k_prep(
    const int* __restrict__ labels, float* __restrict__ ns,
    float* __restrict__ out, int out_size, int* __restrict__ nact,
    ushort2* __restrict__ list, float* __restrict__ cscale) {
  const int tid = (int)threadIdx.x;
  const int b = (int)blockIdx.x;
  for (int i = b * 256 + tid; i < kM; i += 64 * 256) ns[i] = 0.f;
  if (b != 0) return;
  __shared__ int s_lab[kT];
  if (tid < kT) s_lab[tid] = labels[tid];
  if (tid == 0) *nact = 0;
  for (int i = tid; i < out_size; i += 256) out[i] = 0.f;
  __syncthreads();
  if (tid < kT) {
    int m = 0;
    for (int u = 0; u < kT; ++u) m += (s_lab[u] == s_lab[tid]) ? 1 : 0;
    cscale[tid] = 1.f / ((float)(m * kV - 1) * (float)kM);
  }
  for (int p = tid; p < kT * kT; p += 256) {
    const int ti = p >> 5, tj = p & 31;
    if (s_lab[ti] == s_lab[tj]) {
      int base = atomicAdd(nact, 16);
#pragma unroll
      for (int a = 0; a < 4; ++a)
#pragma unroll
        for (int bb = 0; bb < 4; ++bb) {
          ushort2 e;
          e.x = (unsigned short)(ti * 4 + a);  // bi 0..127
          e.y = (unsigned short)(tj * 4 + bb); // bj 0..127
          list[base + a * 4 + bb] = e;
        }
    }
  }
}

// ---------------- K1: gather (coalesced row staging) ----------------
__global__ __launch_bounds__(256) void k_gather(
    const float* __restrict__ feat, const int* __restrict__ binds,
    const int* __restrict__ sinds, unsigned short* __restrict__ FT) {
  const int b = (int)blockIdx.x;   // 0..7
  const int c = (int)blockIdx.y;   // 0..255
  __shared__ alignas(16) float row[kHW];
  __shared__ int s_match[kT + 1];
  if (threadIdx.x == 0) {
    int cnt = 0;
    for (int t = 0; t < kT; ++t)
      if (binds[t] == b) s_match[1 + cnt++] = t;
    s_match[0] = cnt;
  }
  __syncthreads();
  const int cnt = s_match[0];
  if (cnt == 0) return;
  const float4* src4 = (const float4*)(feat + ((size_t)b * kC + c) * kHW);
  for (int i = (int)threadIdx.x; i < kHW / 4; i += 256)
    ((float4*)row)[i] = src4[i];
  __syncthreads();
  unsigned short* dst = FT + (size_t)c * kM;
  for (int mi = 1; mi <= cnt; ++mi) {
    const int t = s_match[mi];
    const int p = sinds[t * kV + threadIdx.x];
    dst[t * kV + threadIdx.x] = f2bf(row[p]);
  }
}

// ---------------- K2: transpose + normalize ----------------
__global__ __launch_bounds__(256) void k_norm(
    const unsigned short* __restrict__ FT, unsigned short* __restrict__ F) {
  constexpr int PAD = 40;  // 32 vecs + 8 pad (80 B rows: breaks bank aliasing)
  const int v0 = (int)blockIdx.x * 32;
  __shared__ alignas(16) unsigned short tile[kC][PAD];
  __shared__ float part[8][32];
  __shared__ float s_inv[32];
  const int tid = (int)threadIdx.x;
  {
    const int p4 = tid & 3, cb = tid >> 2;  // 4x16B per 64B c-row
    for (int c = cb; c < kC; c += 64) {
      int4 d = *(const int4*)(FT + (size_t)c * kM + v0 + p4 * 8);
      *(int4*)&tile[c][p4 * 8] = d;
    }
  }
  __syncthreads();
  {
    const int v = tid & 31, oct = tid >> 5;
    float ss = 0.f;
    for (int c = oct * 32; c < oct * 32 + 32; ++c) {
      float x = bf2f(tile[c][v]);
      ss += x * x;
    }
    part[oct][v] = ss;
  }
  __syncthreads();
  if (tid < 32) {
    float ss = 0.f;
#pragma unroll
    for (int o = 0; o < 8; ++o) ss += part[o][tid];
    s_inv[tid] = 1.0f / fmaxf(sqrtf(ss), 1e-12f);
  }
  __syncthreads();
#pragma unroll
  for (int p = 0; p < 4; ++p) {
    const int chunk = p * 256 + tid;
    const int v = chunk >> 5, c0 = (chunk & 31) << 3;
    const float inv = s_inv[v];
    alignas(16) unsigned short o[8];
#pragma unroll
    for (int k = 0; k < 8; ++k) o[k] = f2bf(bf2f(tile[c0 + k][v]) * inv);
    *(int4*)(F + (size_t)(v0 + v) * kC + c0) = *(const int4*)o;
  }
}

// ---------------- K3: negative sweep -> ns[row] ----------------
// grid 512 x 512 threads: panel = bid&7 (1024 cols, XCD-pinned: 512 KB
// B-panel resident in that XCD's L2), rowblock rb = bid>>3 (128 rows).
// Wave grid 4 (wr) x 2 (wc): each wave computes 32 rows x 32 cols per tile.
// Single 32 KB LDS buffer; 2 blocks/CU x 8 waves = 16 waves/CU.
__global__ __launch_bounds__(512, 4) void k_neg(
    const unsigned short* __restrict__ F, const int* __restrict__ labels,
    float* __restrict__ ns) {
  const int tid = (int)threadIdx.x;
  const int w = tid >> 6, lane = tid & 63, q = lane >> 4, l16 = lane & 15;
  const int wr = w >> 1, wc = w & 1;
  const int bid = (int)blockIdx.x;  // 0..511
  const int panel = bid & 7;        // 0..7 (XCD-pinned 1024-col panel)
  const int rb = bid >> 3;          // 0..63 (128-row block)
  const int row0 = rb * 128;
  __shared__ alignas(16) unsigned short Bt[64 * kC];  // 32 KB, swizzled
  __shared__ int s_lab[kT];
  __shared__ int s_tiles[16];
  __shared__ int s_nt;
  __shared__ float s_red[8][32];
  if (tid < kT) s_lab[tid] = labels[tid];
  __syncthreads();
  const int labr = s_lab[rb >> 1];  // one t per 128-row block
  if (tid == 0) {  // compacted negative-tile list (block-uniform skip)
    int n = 0;
    for (int ct = panel * 16; ct < panel * 16 + 16; ++ct)
      if (s_lab[ct >> 2] != labr) s_tiles[n++] = ct;
    s_nt = n;
  }
  __syncthreads();
  const int nt = s_nt;
  if (nt == 0) return;

  // --- A prologue: two 64-row passes through Bt -> af[2][8] (64 VGPR).
  // Sourcing af from soon-overwritten LDS makes remat impossible (proven
  // resident at VGPR=88 in round 6).
  short8 af[2][8];
  stage_tile8(F, Bt, rb * 2, tid);      // rows row0 .. row0+63
  __syncthreads();
  if (wr < 2) {
#pragma unroll
    for (int rg = 0; rg < 2; ++rg) {
      const int ja = wr * 32 + rg * 16 + l16;  // local row 0..63
      const unsigned short* arow = Bt + ja * kC;
#pragma unroll
      for (int ks = 0; ks < 8; ++ks)
        af[rg][ks] =
            *(const short8*)(arow + (((ks * 4 + q) ^ (ja & 31)) << 3));
    }
  }
  __syncthreads();
  stage_tile8(F, Bt, rb * 2 + 1, tid);  // rows row0+64 .. row0+127
  __syncthreads();
  if (wr >= 2) {
#pragma unroll
    for (int rg = 0; rg < 2; ++rg) {
      const int ja = (wr - 2) * 32 + rg * 16 + l16;
      const unsigned short* arow = Bt + ja * kC;
#pragma unroll
      for (int ks = 0; ks < 8; ++ks)
        af[rg][ks] =
            *(const short8*)(arow + (((ks * 4 + q) ^ (ja & 31)) << 3));
    }
  }

  // B columns for this wave: jb0 = wc*32 + l16, jb1 = jb0 + 16.
  // (jb0 & 31) == l16, (jb1 & 31) == l16 | 16  =>  bofs1 = bofs0 ^ 128.
  const unsigned short* bc0 = Bt + (wc * 32 + l16) * kC;
  const unsigned short* bc1 = bc0 + 16 * kC;
  int bofs[8];
#pragma unroll
  for (int ks = 0; ks < 8; ++ks) bofs[ks] = ((ks * 4 + q) ^ l16) << 3;

  float sacc[2][4] = {};
  for (int it = 0; it < nt; ++it) {
    __syncthreads();  // prior readers (af prologue / previous tile) done
    stage_tile8(F, Bt, s_tiles[it], tid);
    __syncthreads();  // compiler drains vmcnt(0) before the barrier
    f32x4 a00 = {0.f, 0.f, 0.f, 0.f}, a01 = a00, a10 = a00, a11 = a00;
#pragma unroll
    for (int ks = 0; ks < 8; ++ks) {
      short8 b0 = *(const short8*)(bc0 + bofs[ks]);
      short8 b1 = *(const short8*)(bc1 + (bofs[ks] ^ 128));
      a00 = __builtin_amdgcn_mfma_f32_16x16x32_bf16(af[0][ks], b0, a00, 0, 0, 0);
      a01 = __builtin_amdgcn_mfma_f32_16x16x32_bf16(af[0][ks], b1, a01, 0, 0, 0);
      a10 = __builtin_amdgcn_mfma_f32_16x16x32_bf16(af[1][ks], b0, a10, 0, 0, 0);
      a11 = __builtin_amdgcn_mfma_f32_16x16x32_bf16(af[1][ks], b1, a11, 0, 0, 0);
    }
#pragma unroll
    for (int r = 0; r < 4; ++r) {
      sacc[0][r] += __expf(fmaf(a00[r], 2.f, -2.f)) +
                    __expf(fmaf(a01[r], 2.f, -2.f));
      sacc[1][r] += __expf(fmaf(a10[r], 2.f, -2.f)) +
                    __expf(fmaf(a11[r], 2.f, -2.f));
    }
  }

  // Row reduction: sum over the wave's 16 columns (l16 lanes), then across
  // the two wc-waves sharing each row, then one atomicAdd per row.
#pragma unroll
  for (int rg = 0; rg < 2; ++rg)
#pragma unroll
    for (int r = 0; r < 4; ++r) {
      float v = sacc[rg][r];
      v += __shfl_xor(v, 1, 64);
      v += __shfl_xor(v, 2, 64);
      v += __shfl_xor(v, 4, 64);
      v += __shfl_xor(v, 8, 64);
      if (l16 == 0) s_red[w][rg * 16 + q * 4 + r] = v;
    }
  __syncthreads();
  if (tid < 128) {
    const int rr = tid >> 5, e = tid & 31;  // row = row0 + rr*32 + e
    float v = s_red[rr * 2][e] + s_red[rr * 2 + 1][e];
    atomicAdd(&ns[row0 + tid], v);
  }
}

// ---------------- K4: positive sweep -> loss (list-driven) ----------------
__global__ __launch_bounds__(256, 3) void k_pos(
    const unsigned short* __restrict__ F, const float* __restrict__ ns,
    const int* __restrict__ nact, const ushort2* __restrict__ list,
    const float* __restrict__ cscale, float* __restrict__ out) {
  const int tid = (int)threadIdx.x;
  const int w = tid >> 6, lane = tid & 63, q = lane >> 4, l16 = lane & 15;
  const int wr = w >> 1, wc = w & 1;
  __shared__ alignas(16) unsigned short Bt[64 * kC];  // 32 KB, swizzled
  __shared__ float s_pos[4];
  const int n = *nact;

  const int jb0 = wc * 32 + l16, jb1 = wc * 32 + 16 + l16;
  int bofs0[8], bofs1[8];
#pragma unroll
  for (int ks = 0; ks < 8; ++ks) {
    bofs0[ks] = (((ks * 4 + q) ^ (jb0 & 31)) << 3);
    bofs1[ks] = (((ks * 4 + q) ^ (jb1 & 31)) << 3);
  }
  const unsigned short* bc0 = (const unsigned short*)Bt + jb0 * kC;
  const unsigned short* bc1 = (const unsigned short*)Bt + jb1 * kC;

  float pos = 0.f;
  for (int idx = (int)blockIdx.x; idx < n; idx += (int)gridDim.x) {
    const ushort2 e = list[idx];
    const int bi = e.x, bj = e.y;
    stage_tile4(F, Bt, bj, tid);  // async; drained at the barrier below

    short8 af[2][8];
#pragma unroll
    for (int rg = 0; rg < 2; ++rg) {
      const int row = bi * 64 + wr * 32 + rg * 16 + l16;
#pragma unroll
      for (int ks = 0; ks < 8; ++ks)
        af[rg][ks] = *(const short8*)((const short*)F + (size_t)row * kC +
                                      ks * 32 + q * 8);
    }
    float nsv[2][4];
#pragma unroll
    for (int rg = 0; rg < 2; ++rg)
#pragma unroll
      for (int r = 0; r < 4; ++r)
        nsv[rg][r] = ns[bi * 64 + wr * 32 + rg * 16 + q * 4 + r];
    const float scale = cscale[bi >> 2];

    __syncthreads();  // B tile staged (+ af/nsv drained by vmcnt)

    f32x4 a00 = {0.f, 0.f, 0.f, 0.f}, a01 = a00, a10 = a00, a11 = a00;
#pragma unroll
    for (int ks = 0; ks < 8; ++ks) {
      short8 b0 = *(const short8*)(bc0 + bofs0[ks]);
      short8 b1 = *(const short8*)(bc1 + bofs1[ks]);
      a00 = __builtin_amdgcn_mfma_f32_16x16x32_bf16(af[0][ks], b0, a00, 0, 0, 0);
      a01 = __builtin_amdgcn_mfma_f32_16x16x32_bf16(af[0][ks], b1, a01, 0, 0, 0);
      a10 = __builtin_amdgcn_mfma_f32_16x16x32_bf16(af[1][ks], b0, a10, 0, 0, 0);
      a11 = __builtin_amdgcn_mfma_f32_16x16x32_bf16(af[1][ks], b1, a11, 0, 0, 0);
    }

    float tpos = 0.f;
#pragma unroll
    for (int rg = 0; rg < 2; ++rg)
#pragma unroll
      for (int cg = 0; cg < 2; ++cg) {
        const f32x4 acc = (rg == 0) ? (cg == 0 ? a00 : a01)
                                    : (cg == 0 ? a10 : a11);
        const int jc = bj * 64 + wc * 32 + cg * 16 + l16;
#pragma unroll
        for (int r = 0; r < 4; ++r) {
          const int i = bi * 64 + wr * 32 + rg * 16 + q * 4 + r;
          if (i != jc) {
            float d = fmaf(acc[r], 2.f, -2.f);
            tpos += d - __logf(__expf(d) + nsv[rg][r]);
          }
        }
      }
    pos += scale * tpos;
    __syncthreads();  // all waves done reading Bt before next stage
  }

#pragma unroll
  for (int m = 1; m < 64; m <<= 1) pos += __shfl_xor(pos, m, 64);
  if (lane == 0) s_pos[w] = pos;
  __syncthreads();
  if (tid == 0)
    atomicAdd(out, -(s_pos[0] + s_pos[1] + s_pos[2] + s_pos[3]));
}

extern "C" void kernel_launch(void* const* d_in, const int* in_sizes, int n_in,
                              void* d_out, int out_size, void* d_ws,
                              size_t ws_size, hipStream_t stream) {
  const float* feat = (const float*)d_in[0];
  const int* binds = (const int*)d_in[1];
  const int* sinds = (const int*)d_in[2];
  const int* labels = (const int*)d_in[3];
  float* out = (float*)d_out;
  unsigned short* FT = (unsigned short*)d_ws;            // 4 MB  [256][8192]
  unsigned short* F = FT + (size_t)kC * kM;              // 4 MB  [8192][256]
  float* ns = (float*)(F + (size_t)kM * kC);             // 32 KB [8192]
  int* nact = (int*)(ns + kM);                           // 4 B (+pad)
  float* cscale = (float*)(nact + 8);                    // 128 B [32]
  ushort2* list = (ushort2*)(cscale + 32);               // 64 KB [16384]

  k_prep<<<64, 256, 0, stream>>>(labels, ns, out, out_size, nact, list, cscale);
  k_gather<<<dim3(8, kC), 256, 0, stream>>>(feat, binds, sinds, FT);
  k_norm<<<kM / 32, 256, 0, stream>>>(FT, F);
  k_neg<<<dim3(512), 512, 0, stream>>>(F, labels, ns);
  k_pos<<<768, 256, 0, stream>>>(F, ns, nact, list, cscale, out);
}